// Round 4
// baseline (429.396 us; speedup 1.0000x reference)
//
#include <hip/hip_runtime.h>

#define N_ 4
#define D_ 16
#define H_ 112
#define W_ 112
#define C_ 64

#define DO_ 2
#define HO_ 2
#define DT_ (D_ / DO_)                     // 8 d-tiles
#define HTILES (H_ / HO_)                  // 56 h-tiles
#define WAVES_PER_BLOCK 4
#define HGROUPS (HTILES / WAVES_PER_BLOCK) // 14
#define WSPLIT 4
#define WQ (W_ / WSPLIT)                   // 28 output cols/wave -> 30 steps = 8 supersteps
#define NWG (N_ * DT_ * HGROUPS * WSPLIT)  // 1792 blocks
#define CB (C_ * 4)                        // 256 B per w-column
#define ROWB (W_ * CB)                     // 28672 B per (n,d,h) row

// Zero page for SAME-padding halo rows (.bss = zero-initialized, never written).
__device__ float zpage[W_ * C_];

// Accumulate-forward FMA (verified in r3): input col ci scatters into 3 live
// output-col accumulator sets N=ci+1(kw0), M=ci(kw1), O=ci-1(kw2); KWM bitmask
// {1=N,2=M,4=O} drops contributions to neighbor-owned boundary columns.
template <int U, int DR, int HR, int KWM>
__device__ __forceinline__ void stream_fma(float (&acc)[3][2][2],
                                           const float (&wt)[3][3][3],
                                           float v) {
  constexpr int iN = U % 3;
  constexpr int iM = (U + 5) % 3;
  constexpr int iO = (U + 4) % 3;
#pragma unroll
  for (int od = (DR >= 2 ? DR - 2 : 0); od <= (DR < 1 ? DR : 1); ++od)
#pragma unroll
    for (int oh = (HR >= 2 ? HR - 2 : 0); oh <= (HR < 1 ? HR : 1); ++oh) {
      if (KWM & 1) acc[iN][od][oh] += v * wt[DR - od][HR - oh][0];
      if (KWM & 2) acc[iM][od][oh] += v * wt[DR - od][HR - oh][1];
      if (KWM & 4) acc[iO][od][oh] += v * wt[DR - od][HR - oh][2];
    }
}

#define F_(U, M, DR, HR) stream_fma<U, DR, HR, M>(acc, wt, lv[DR][HR]);
#define F16(U, M)                                               \
  F_(U,M,0,0) F_(U,M,0,1) F_(U,M,0,2) F_(U,M,0,3)               \
  F_(U,M,1,0) F_(U,M,1,1) F_(U,M,1,2) F_(U,M,1,3)               \
  F_(U,M,2,0) F_(U,M,2,1) F_(U,M,2,2) F_(U,M,2,3)               \
  F_(U,M,3,0) F_(U,M,3,1) F_(U,M,3,2) F_(U,M,3,3)

// store completed O set (col = current col - 2 in vb terms) and re-zero it
#define STORE4(U)                                                             \
  *(float*)(ox[0][0] + (vb - 2*CB)) = acc[(U+4)%3][0][0]; acc[(U+4)%3][0][0] = 0.f; \
  *(float*)(ox[0][1] + (vb - 2*CB)) = acc[(U+4)%3][0][1]; acc[(U+4)%3][0][1] = 0.f; \
  *(float*)(ox[1][0] + (vb - 2*CB)) = acc[(U+4)%3][1][0]; acc[(U+4)%3][1][0] = 0.f; \
  *(float*)(ox[1][1] + (vb - 2*CB)) = acc[(U+4)%3][1][1]; acc[(U+4)%3][1][1] = 0.f;

// One compute step: 16 ds_reads (4B/lane, 2-way bank alias = free) + 108 FMA.
// All LDS offsets are compile-time immediates off one per-lane base.
#define DSTEP(U, M, Q, DOST)                                          \
  {                                                                   \
    float lv[4][4];                                                   \
    _Pragma("unroll") for (int dr = 0; dr < 4; ++dr)                  \
      _Pragma("unroll") for (int hr = 0; hr < 4; ++hr)                \
        lv[dr][hr] = lp[(((dr)*10 + (hr))*4 + (Q)) * 64];             \
    F16(U, M)                                                         \
    if (DOST) { STORE4(U) }                                           \
    vb += CB;                                                         \
  }

// Stage 4 columns (1KB contiguous burst per stream) for this wave's 10 streams:
// global_load_dwordx4 (64 lanes x 16B = 1KB page-friendly) -> ds_write_b128.
// Per-lane source offset clamped into the row; over-fetched halo halves are
// never consumed (edge-step KWM masks skip them).
#define STAGE_SS(T)                                                   \
  {                                                                   \
    int off = vb16 + ((w0 - 1 + 4*(T)) * CB);                         \
    off = off < 0 ? 0 : off;                                          \
    off = off > (ROWB - 16) ? (ROWB - 16) : off;                      \
    _Pragma("unroll") for (int j = 0; j < 10; ++j) {                  \
      float4 v = *(const float4*)(sb[j] + off);                       \
      *(float4*)(sw + j*1024) = v;                                    \
    }                                                                 \
  }

// Raw barrier + manual waitcnt (no compiler vmcnt(0) __syncthreads bloat);
// asm "memory" clobbers fence compiler reordering across the rendezvous.
#define SYNC_IN()                                                            \
  asm volatile("s_waitcnt vmcnt(0) lgkmcnt(0)" ::: "memory");                \
  __builtin_amdgcn_s_barrier();                                              \
  asm volatile("" ::: "memory");
#define SYNC_OUT()                                                           \
  asm volatile("" ::: "memory");                                             \
  __builtin_amdgcn_s_barrier();

#define SS4(T, U0,M0,S0, U1,M1,S1, U2,M2,S2, U3,M3,S3)  \
  STAGE_SS(T) SYNC_IN()                                  \
  DSTEP(U0,M0,0,S0) DSTEP(U1,M1,1,S1)                    \
  DSTEP(U2,M2,2,S2) DSTEP(U3,M3,3,S3)                    \
  SYNC_OUT()

__global__ __launch_bounds__(256, 4)   // VGPR cap 128; live set ~95 (r2 lesson: margin!)
void dwconv3d_kernel(const float* __restrict__ x,
                     const float* __restrict__ wgt,
                     float* __restrict__ out) {
    __shared__ float lds[40][4][64];   // 40 streams x 4 cols x 64 ch = 40 KB -> 4 blocks/CU

    // bijective XCD-aware swizzle (NWG % 8 == 0)
    int b = blockIdx.x;
    b = (b & 7) * (NWG / 8) + (b >> 3);
    const int wh = b % WSPLIT; b /= WSPLIT;
    const int hg = b % HGROUPS; b /= HGROUPS;
    const int dt = b % DT_;     b /= DT_;
    const int n  = b;

    const int c   = threadIdx.x & 63;
    const int wid = __builtin_amdgcn_readfirstlane(threadIdx.x >> 6);

    const int d0 = dt * DO_;
    const int h0 = (hg * WAVES_PER_BLOCK + wid) * HO_;
    const int w0 = wh * WQ;
    const bool wend = (w0 + WQ < W_);   // block-uniform

    // per-lane weights (27 VGPRs), coalesced
    float wt[3][3][3];
#pragma unroll
    for (int kd = 0; kd < 3; ++kd)
#pragma unroll
      for (int kh = 0; kh < 3; ++kh)
#pragma unroll
        for (int kw = 0; kw < 3; ++kw)
          wt[kd][kh][kw] = wgt[((kd * 3 + kh) * 3 + kw) * C_ + c];

    // This wave stages d-row (d0-1+wid), h-rows hg*8-1 .. hg*8+8 (10 streams).
    const char* sb[10];
    {
      const int d = d0 - 1 + wid;
      const bool dv = (d >= 0) && (d < D_);
#pragma unroll
      for (int j = 0; j < 10; ++j) {
        const int h = hg * 8 - 1 + j;
        const bool hv = (h >= 0) && (h < H_);
        sb[j] = (dv && hv)
            ? (const char*)(x + (size_t)((n * D_ + d) * H_ + h) * W_ * C_)
            : (const char*)zpage;
      }
    }

    // LDS bases: write side (this wave's 10 streams), read side (per-lane)
    char* sw = (char*)lds + wid * 10240 + c * 16;
    const float* lp = (const float*)((const char*)lds + wid * 2048 + c * 4);

    // 4 wave-uniform output row bases
    char* ox[2][2];
#pragma unroll
    for (int od = 0; od < 2; ++od)
#pragma unroll
      for (int oh = 0; oh < 2; ++oh)
        ox[od][oh] = (char*)(out +
            (size_t)((n * D_ + d0 + od) * H_ + (h0 + oh)) * W_ * C_);

    float acc[3][2][2];
#pragma unroll
    for (int i = 0; i < 3; ++i)
#pragma unroll
      for (int od = 0; od < 2; ++od)
#pragma unroll
        for (int oh = 0; oh < 2; ++oh) acc[i][od][oh] = 0.f;

    const int vb16 = c * 16;                               // stage lane offset
    unsigned vb = (unsigned)(w0 * CB) + (unsigned)(c * 4); // store offset tracker

    // 30 steps (cols w0-1 .. w0+28) = 8 supersteps of 4 cols (last: 2 used).
    // Step s: U = s%6; masks: s=0 -> 1 (or 0 if w0==0: col -1 never consumed),
    // s=1 -> 3, s=2..27 -> 7, s=28 -> 6, s=29 -> 4 iff wend; stores from s=2.
    if (w0) { SS4(0, 0,1,0, 1,3,0, 2,7,1, 3,7,1) }
    else    { SS4(0, 0,0,0, 1,3,0, 2,7,1, 3,7,1) }
#pragma unroll 1
    for (int r = 0; r < 2; ++r) {
      const int t = 1 + r * 3;
      SS4(t,     4,7,1, 5,7,1, 0,7,1, 1,7,1)
      SS4(t + 1, 2,7,1, 3,7,1, 4,7,1, 5,7,1)
      SS4(t + 2, 0,7,1, 1,7,1, 2,7,1, 3,7,1)
    }
    // superstep 7: s=28 (q0), s=29 (q1); staged cols w0+29/30 are dead weight
    STAGE_SS(7) SYNC_IN()
    DSTEP(4, 6, 0, 1)
    if (wend) { DSTEP(5, 4, 1, 1) }
    else      { DSTEP(5, 0, 1, 1) }
}

extern "C" void kernel_launch(void* const* d_in, const int* in_sizes, int n_in,
                              void* d_out, int out_size, void* d_ws, size_t ws_size,
                              hipStream_t stream) {
    const float* x   = (const float*)d_in[0];
    const float* wgt = (const float*)d_in[1];
    float* out = (float*)d_out;

    dim3 grid(NWG);   // 1792 blocks; LDS 40KB -> 4 blocks/CU resident
    dim3 block(256);
    dwconv3d_kernel<<<grid, block, 0, stream>>>(x, wgt, out);
}